// Round 9
// baseline (364.346 us; speedup 1.0000x reference)
//
#include <hip/hip_runtime.h>

#define AANG 180
#define NN 256
#define BCH 12

#ifndef M_PI
#define M_PI 3.14159265358979323846
#endif

__device__ __forceinline__ int iclamp(int v, int lo, int hi) {
    return v < lo ? lo : (v > hi ? hi : v);
}

// DPP row_ror add: v += rotate-within-16-lane-row(v, N). VALU only, no LDS pipe.
template <int CTRL>
__device__ __forceinline__ float dpp_add(float v) {
    int r = __builtin_amdgcn_update_dpp(0, __float_as_int(v), CTRL, 0xF, 0xF, true);
    return v + __int_as_float(r);
}

// ---------------- Radon v19 (R21 verbatim, measured 163us -- R22's deeper
// unroll was neutral, reverted): 90-deg pairing + MLP-phased trip body.
//   P1: all 6 addresses, all 12 ds_read_b64 issued back-to-back (MLP=12)
//   P2: all 6 lerps + column accumulates (ILP=6)
//   P3: all 6 DPP chains interleaved + batched atomics.
#define LSTR2 259
#define NPAIRS 65

__global__ __launch_bounds__(1024, 4)
void radon_kernel(const float* __restrict__ x, float* __restrict__ partial,
                  const float* __restrict__ Wq, const float* __restrict__ Wk,
                  const float* __restrict__ Wv, float* __restrict__ WqT,
                  float* __restrict__ WkT, float* __restrict__ WvT) {
    __shared__ float2 ptile[NPAIRS * LSTR2];  // 134,680 B
    __shared__ float rowsum[3][257];          // 3,084 B
    int blk = blockIdx.x;        // ((n*2)+h)*30 + g
    int tid = threadIdx.x;

    // --- wtrans prologue: 720 blocks x 45 elements = 32400 (exact) ---
    if (tid < 45) {
        int idx = blk * 45 + tid;
        int p = idx / AANG;
        int j = idx - p * AANG;
        int src = j * AANG + p;
        WqT[idx] = Wq[src];
        WkT[idx] = Wk[src];
        WvT[idx] = Wv[src];
    }

    int g = blk % 30;            // angle group: theta = 3g + k, k=0..2
    int t = blk / 30;
    int h = t & 1;
    int n = t >> 1;
    const float* img = x + (size_t)n * NN * NN;

    int l = tid & 63;            // lane in wave
    int wv = tid >> 6;           // wave 0..15
    int fxl = l & 15;            // fx within wave
    int sub = l >> 4;            // i-phase 0..3 (= DPP row id)
    int fx_i = wv * 16 + fxl;    // detector column 0..255
    float fx = (float)fx_i;

    if (tid < 3 * 257) ((float*)rowsum)[tid] = 0.0f;  // zeroed before 1st sync

    // per-angle constants (theta in [0,89] -> c >= cos(89deg) > 0.017)
    float c[3], s[3], xcon[3], dcon[3], acc[3];
#pragma unroll
    for (int k = 0; k < 3; ++k) {
        int a = 3 * g + k;
        float th = (float)((double)a * (M_PI / 180.0));
        c[k] = cosf(th);
        s[k] = sinf(th);
        float kx = -128.0f * (c[k] + s[k] - 1.0f);
        float ky = -128.0f * (c[k] - s[k] - 1.0f);
        xcon[k] = c[k] * fx + kx;    // sx = fma(s, fy, xcon)
        dcon[k] = -s[k] * fx + ky;   // sy = fma(c, fy, dcon)
        acc[k] = 0.0f;
    }

    for (int b = 0; b < 2; ++b) {
        int bb = h * 2 + b;                 // global band 0..3 (64 rows each)
        int R0 = bb * 64 - 1;               // valid floor(sy) in [R0, R0+lrmax]
        unsigned lrmax = (bb == 3) ? 64u : 63u;
        int npr = (int)lrmax + 1;           // pairs staged: lr = 0..lrmax
        float R0f = (float)R0;              // row guard passes <=> sy in [R0f, R1f)
        float R1f = (float)(R0 + (int)lrmax + 1);

        if (b) __syncthreads();             // band0 compute done before restage
        // stage pairs: ptile[r*LSTR2+cc] = {img[R0+r][cc-1], img[R0+r+1][cc-1]}
        for (int idx = tid; idx < npr * LSTR2; idx += 1024) {
            int r = idx / LSTR2;
            int cc = idx - r * LSTR2;
            int gc = cc - 1;
            int gr0 = R0 + r;
            int gr1 = gr0 + 1;
            bool cok = (gc >= 0) && (gc < NN);
            float v0 = (cok && gr0 >= 0 && gr0 < NN) ? img[gr0 * NN + gc] : 0.0f;
            float v1 = (cok && gr1 < NN) ? img[gr1 * NN + gc] : 0.0f;
            ptile[idx] = make_float2(v0, v1);
        }
        __syncthreads();

        // per-lane 3-angle union of valid-i intervals (conservative slack;
        // in-loop guard enforces exactness); i ranges over [0, 257)
        int ilo = 257, ihi = 0;
#pragma unroll
        for (int k = 0; k < 3; ++k) {
            float t0 = (R0f - dcon[k]) / c[k];   // c > 0 -> t0 < t1
            float t1 = (R1f - dcon[k]) / c[k];
            int lo_k = max(0, (int)floorf(t0));
            int hi_k = min(257, (int)ceilf(t1) + 1);
            if (hi_k > lo_k) {
                ilo = min(ilo, lo_k);
                ihi = max(ihi, hi_k);
            }
        }
        // wave-uniform interval -> lockstep loop (aligned LDS access, uniform
        // branch, and same-i DPP rows stay in step)
        for (int off = 1; off < 64; off <<= 1) {
            ilo = min(ilo, __shfl_xor(ilo, off));
            ihi = max(ihi, __shfl_xor(ihi, off));
        }

        for (int i = ilo + sub; i < ihi; i += 8) {
            int iB = i + 4;
            float fyA = (float)i;
            float fyB = (float)iB;
            bool inbB = (iB < ihi);

            // ---- P1: addresses + ALL 12 ds_read_b64 issued together ----
            float2 lo2v[6], hi2v[6];
            float wxv[6], wyv[6];
            bool okv[6];
#pragma unroll
            for (int k = 0; k < 3; ++k) {
                {   // sample A
                    float sy = __builtin_fmaf(c[k], fyA, dcon[k]);
                    float sx = __builtin_fmaf(s[k], fyA, xcon[k]);
                    float iyf = floorf(sy), ixf = floorf(sx);
                    int lr = (int)iyf - R0, lc = (int)ixf + 1;
                    bool ok = ((unsigned)lr <= lrmax) & ((unsigned)lc <= 256u);
                    int ad = ok ? (lr * LSTR2 + lc) : 0;
                    lo2v[k] = ptile[ad];
                    hi2v[k] = ptile[ad + 1];
                    wxv[k] = sx - ixf;
                    wyv[k] = sy - iyf;
                    okv[k] = ok;
                }
                {   // sample B
                    float sy = __builtin_fmaf(c[k], fyB, dcon[k]);
                    float sx = __builtin_fmaf(s[k], fyB, xcon[k]);
                    float iyf = floorf(sy), ixf = floorf(sx);
                    int lr = (int)iyf - R0, lc = (int)ixf + 1;
                    bool ok = inbB & ((unsigned)lr <= lrmax) & ((unsigned)lc <= 256u);
                    int ad = ok ? (lr * LSTR2 + lc) : 0;
                    lo2v[3 + k] = ptile[ad];
                    hi2v[3 + k] = ptile[ad + 1];
                    wxv[3 + k] = sx - ixf;
                    wyv[3 + k] = sy - iyf;
                    okv[3 + k] = ok;
                }
            }

            // ---- P2: all 6 lerps + column accumulates ----
            bool coliA = (i < 256), rowiA = (i >= 1);
            bool coliB = (iB < 256);
            float vA[3], vB[3];
#pragma unroll
            for (int k = 0; k < 3; ++k) {
                float wy = wyv[k], wx = wxv[k];
                float wx1 = 1.0f - wx, wy1 = 1.0f - wy;
                float v = wy1 * (wx1 * lo2v[k].x + wx * hi2v[k].x) +
                          wy  * (wx1 * lo2v[k].y + wx * hi2v[k].y);
                acc[k] += (okv[k] && coliA) ? v : 0.0f;
                vA[k] = (okv[k] && rowiA) ? v : 0.0f;
            }
#pragma unroll
            for (int k = 0; k < 3; ++k) {
                float wy = wyv[3 + k], wx = wxv[3 + k];
                float wx1 = 1.0f - wx, wy1 = 1.0f - wy;
                float v = wy1 * (wx1 * lo2v[3 + k].x + wx * hi2v[3 + k].x) +
                          wy  * (wx1 * lo2v[3 + k].y + wx * hi2v[3 + k].y);
                acc[k] += (okv[3 + k] && coliB) ? v : 0.0f;
                vB[k] = okv[3 + k] ? v : 0.0f;   // iB >= 4 so rowi always true
            }

            // ---- P3: 6 independent DPP chains, interleaved ----
            float rA0 = vA[0], rA1 = vA[1], rA2 = vA[2];
            float rB0 = vB[0], rB1 = vB[1], rB2 = vB[2];
            rA0 = dpp_add<0x121>(rA0); rA1 = dpp_add<0x121>(rA1);
            rA2 = dpp_add<0x121>(rA2); rB0 = dpp_add<0x121>(rB0);
            rB1 = dpp_add<0x121>(rB1); rB2 = dpp_add<0x121>(rB2);
            rA0 = dpp_add<0x122>(rA0); rA1 = dpp_add<0x122>(rA1);
            rA2 = dpp_add<0x122>(rA2); rB0 = dpp_add<0x122>(rB0);
            rB1 = dpp_add<0x122>(rB1); rB2 = dpp_add<0x122>(rB2);
            rA0 = dpp_add<0x124>(rA0); rA1 = dpp_add<0x124>(rA1);
            rA2 = dpp_add<0x124>(rA2); rB0 = dpp_add<0x124>(rB0);
            rB1 = dpp_add<0x124>(rB1); rB2 = dpp_add<0x124>(rB2);
            rA0 = dpp_add<0x128>(rA0); rA1 = dpp_add<0x128>(rA1);
            rA2 = dpp_add<0x128>(rA2); rB0 = dpp_add<0x128>(rB0);
            rB1 = dpp_add<0x128>(rB1); rB2 = dpp_add<0x128>(rB2);
            if (fxl == 0) {
                atomicAdd(&rowsum[0][i], rA0);
                atomicAdd(&rowsum[1][i], rA1);
                atomicAdd(&rowsum[2][i], rA2);
                if (inbB) {
                    atomicAdd(&rowsum[0][iB], rB0);
                    atomicAdd(&rowsum[1][iB], rB1);
                    atomicAdd(&rowsum[2][iB], rB2);
                }
            }
        }
    }

    __syncthreads();
    size_t base = (((size_t)h * BCH + n) * AANG);
    // column part: sum the 4 sub-phases (lanes l, l^16, l^32, l^48 share fx)
#pragma unroll
    for (int k = 0; k < 3; ++k) {
        acc[k] += __shfl_xor(acc[k], 16);
        acc[k] += __shfl_xor(acc[k], 32);
    }
    if (sub == 0) {
#pragma unroll
        for (int k = 0; k < 3; ++k)
            partial[(base + (3 * g + k)) * NN + fx_i] = acc[k];
    }
    // row part: sino(theta+90)[256-i] = rowsum[k][i], i = 1..256
    if (tid < 3 * 257) {
        int k = tid / 257;
        int i = tid - k * 257;
        if (i >= 1)
            partial[(base + (3 * g + k + 90)) * NN + (256 - i)] = rowsum[k][i];
    }
}

// ---------------- QKV v7 (R13): 8 rows/block. Q,V row-major; Kt scatter-stores.
__global__ void qkv_kernel(const float* __restrict__ partial,
                           const float* __restrict__ WqT, const float* __restrict__ bq,
                           const float* __restrict__ WkT, const float* __restrict__ bk,
                           const float* __restrict__ WvT, const float* __restrict__ bv,
                           float* __restrict__ Q, float* __restrict__ Kt,
                           float* __restrict__ V) {
    __shared__ float srow_t[AANG][8];
    int blk = blockIdx.x;  // n*32 + i8
    int n = blk >> 5;
    int i0 = (blk & 31) * 8;
    int tid = threadIdx.x;  // 256
    const size_t HOFF = (size_t)BCH * AANG * NN;
    if (tid < AANG) {
        size_t idx = (((size_t)n) * AANG + tid) * NN + i0;
        float4 p0 = *(const float4*)&partial[idx];
        float4 p1 = *(const float4*)&partial[idx + 4];
        float4 q0 = *(const float4*)&partial[idx + HOFF];
        float4 q1 = *(const float4*)&partial[idx + HOFF + 4];
        srow_t[tid][0] = p0.x + q0.x;
        srow_t[tid][1] = p0.y + q0.y;
        srow_t[tid][2] = p0.z + q0.z;
        srow_t[tid][3] = p0.w + q0.w;
        srow_t[tid][4] = p1.x + q1.x;
        srow_t[tid][5] = p1.y + q1.y;
        srow_t[tid][6] = p1.z + q1.z;
        srow_t[tid][7] = p1.w + q1.w;
    }
    __syncthreads();
    if (tid < AANG) {
        int j = tid;
        float aq[8], ak[8], av[8];
        float bqv = bq[j], bkv = bk[j], bvv = bv[j];
        for (int r = 0; r < 8; ++r) { aq[r] = bqv; ak[r] = bkv; av[r] = bvv; }
#pragma unroll 4
        for (int p = 0; p < AANG; ++p) {
            float wq = WqT[p * AANG + j];
            float wk = WkT[p * AANG + j];
            float wv = WvT[p * AANG + j];
            float4 sv0 = *(const float4*)&srow_t[p][0];
            float4 sv1 = *(const float4*)&srow_t[p][4];
            aq[0] += sv0.x * wq; ak[0] += sv0.x * wk; av[0] += sv0.x * wv;
            aq[1] += sv0.y * wq; ak[1] += sv0.y * wk; av[1] += sv0.y * wv;
            aq[2] += sv0.z * wq; ak[2] += sv0.z * wk; av[2] += sv0.z * wv;
            aq[3] += sv0.w * wq; ak[3] += sv0.w * wk; av[3] += sv0.w * wv;
            aq[4] += sv1.x * wq; ak[4] += sv1.x * wk; av[4] += sv1.x * wv;
            aq[5] += sv1.y * wq; ak[5] += sv1.y * wk; av[5] += sv1.y * wv;
            aq[6] += sv1.z * wq; ak[6] += sv1.z * wk; av[6] += sv1.z * wv;
            aq[7] += sv1.w * wq; ak[7] += sv1.w * wk; av[7] += sv1.w * wv;
        }
        for (int r = 0; r < 8; ++r) {
            size_t qb = ((size_t)(n * NN + i0 + r)) * AANG + j;
            Q[qb] = aq[r];  // coalesced over j
            V[qb] = av[r];  // row-major, coalesced over j (PV reads coalesced)
        }
        size_t kb = ((size_t)(n * AANG + j)) * NN + i0;
        *(float4*)&Kt[kb]     = make_float4(ak[0], ak[1], ak[2], ak[3]);
        *(float4*)&Kt[kb + 4] = make_float4(ak[4], ak[5], ak[6], ak[7]);
    }
}

// ---------------- Attention v7 (R13): 8 rows/block; coalesced Kt/V streams. ----
__global__ void attn_kernel(const float* __restrict__ Q, const float* __restrict__ Kt,
                            const float* __restrict__ V, float* __restrict__ att_t) {
    __shared__ float qrow[8][AANG];
    __shared__ float prob[8][NN];
    __shared__ float wm[8][4], wsm[8][4];
    int blk = blockIdx.x;  // n*32 + i8
    int n = blk >> 5;
    int i0 = (blk & 31) * 8;
    int tid = threadIdx.x;  // 256: key index k
    int wid = tid >> 6;
    if (tid < AANG) {
#pragma unroll
        for (int r = 0; r < 8; ++r)
            qrow[r][tid] = Q[((size_t)(n * NN + i0 + r)) * AANG + tid];
    }
    __syncthreads();
    float d[8];
#pragma unroll
    for (int r = 0; r < 8; ++r) d[r] = 0.0f;
    const float* kcol = Kt + (size_t)n * AANG * NN + tid;  // lane k: coalesced
#pragma unroll 3
    for (int jj = 0; jj < AANG / 4; ++jj) {
        float kv0 = kcol[(size_t)(jj * 4 + 0) * NN];
        float kv1 = kcol[(size_t)(jj * 4 + 1) * NN];
        float kv2 = kcol[(size_t)(jj * 4 + 2) * NN];
        float kv3 = kcol[(size_t)(jj * 4 + 3) * NN];
#pragma unroll
        for (int r = 0; r < 8; ++r) {
            float4 qv = *(const float4*)&qrow[r][jj * 4];
            d[r] += qv.x * kv0;
            d[r] += qv.y * kv1;
            d[r] += qv.z * kv2;
            d[r] += qv.w * kv3;
        }
    }
    const float rs = 0.0745355992f;  // 1/sqrt(180)
    float l[8], m[8], e[8], s[8];
#pragma unroll
    for (int r = 0; r < 8; ++r) { l[r] = d[r] * rs; m[r] = l[r]; }
    for (int off = 32; off > 0; off >>= 1) {
#pragma unroll
        for (int r = 0; r < 8; ++r) m[r] = fmaxf(m[r], __shfl_xor(m[r], off));
    }
    if ((tid & 63) == 0) {
#pragma unroll
        for (int r = 0; r < 8; ++r) wm[r][wid] = m[r];
    }
    __syncthreads();
#pragma unroll
    for (int r = 0; r < 8; ++r) {
        float mx = fmaxf(fmaxf(wm[r][0], wm[r][1]), fmaxf(wm[r][2], wm[r][3]));
        e[r] = expf(l[r] - mx);
        s[r] = e[r];
    }
    for (int off = 32; off > 0; off >>= 1) {
#pragma unroll
        for (int r = 0; r < 8; ++r) s[r] += __shfl_xor(s[r], off);
    }
    if ((tid & 63) == 0) {
#pragma unroll
        for (int r = 0; r < 8; ++r) wsm[r][wid] = s[r];
    }
    __syncthreads();
#pragma unroll
    for (int r = 0; r < 8; ++r) {
        float dn = wsm[r][0] + wsm[r][1] + wsm[r][2] + wsm[r][3];
        prob[r][tid] = e[r] / dn;
    }
    __syncthreads();
    if (tid < AANG) {
        float a[8];
#pragma unroll
        for (int r = 0; r < 8; ++r) a[r] = 0.0f;
        const float* vcol = V + (size_t)n * NN * AANG + tid;  // lane j: coalesced
#pragma unroll 4
        for (int kk = 0; kk < NN / 4; ++kk) {
            float v0 = vcol[(size_t)(kk * 4 + 0) * AANG];
            float v1 = vcol[(size_t)(kk * 4 + 1) * AANG];
            float v2 = vcol[(size_t)(kk * 4 + 2) * AANG];
            float v3 = vcol[(size_t)(kk * 4 + 3) * AANG];
#pragma unroll
            for (int r = 0; r < 8; ++r) {
                float4 p4 = *(const float4*)&prob[r][kk * 4];
                a[r] += p4.x * v0;
                a[r] += p4.y * v1;
                a[r] += p4.z * v2;
                a[r] += p4.w * v3;
            }
        }
        size_t ob = ((size_t)(n * AANG + tid)) * NN + i0;
        *(float4*)&att_t[ob]     = make_float4(a[0], a[1], a[2], a[3]);
        *(float4*)&att_t[ob + 4] = make_float4(a[4], a[5], a[6], a[7]);
    }
}

// ---------------- Ramp filter v3 (R23): fully-unrolled LITERAL coefficients.
// coef[m] = -2/(pi^2 (2m+1)^2) is compile-time computable; full unroll folds
// it into the fmac as an inline literal -- deletes 128 broadcast LDS reads
// per thread + the coef[] staging. Tap reads and fp order unchanged
// (identical summation order and values vs v2).
__global__ void filter_kernel(const float* __restrict__ att_t, float* __restrict__ filt) {
    __shared__ float scol[512];  // [128..383] = data, rest 0
    int blk = blockIdx.x;  // n*AANG + a
    int tid = threadIdx.x;
    const float* src = &att_t[(size_t)blk * NN];
    scol[tid] = (tid >= 128) ? src[tid - 128] : 0.0f;
    scol[tid + 256] = (tid < 128) ? src[tid + 128] : 0.0f;
    __syncthreads();
    const float* c = &scol[tid + 128];
    float acc = 0.5f * c[0];
#pragma unroll
    for (int m = 0; m < 128; ++m) {
        int d = 2 * m + 1;
        float df = (float)d;
        float cf = -2.0f / (((float)(M_PI * M_PI) * df) * df);  // folded to literal
        acc += cf * (c[-d] + c[d]);
    }
    filt[(size_t)blk * NN + tid] = acc;
}

// ---------------- Backprojection v6 (R23): pair-interleaved float2 tile.
// cols2[q][c] = {f[c], f[c+1]} -> one ds_read_b64 per sample instead of two
// 4B-aligned ds_read_b32 (the radon-v15 trick; halves backproj's dominant
// LDS-issue cost). Accepted-sample values bit-identical: for c0<=254,
// pair.y == f[c0+1] == old cols[c1]; for c0==255 the pair.y operand is
// multiplied by frac==0 (t>255 is guarded off); discarded samples stay
// finite. LDS 73.7+1.4 KB -> still 2 blocks/CU (wave-capped).
#define ACH 36
__global__ __launch_bounds__(1024)
void backproj_kernel(const float* __restrict__ filt, float* __restrict__ out) {
    __shared__ float2 cols2[ACH][NN];   // 73,728 B
    __shared__ float cs[AANG], sn[AANG];
    int blk = blockIdx.x;  // n*64 + rg
    int n = blk >> 6;
    int rg = blk & 63;
    int tid = threadIdx.x;
    int col = tid & 255;
    int rslot = tid >> 8;
    int r = rg * 4 + rslot;
    if (tid < AANG) {
        float th = (float)((double)tid * (M_PI / 180.0));
        cs[tid] = cosf(th);
        sn[tid] = sinf(th);
    }
    float xr = (float)(r - 128);
    float yr = (float)(col - 128);
    float acc = 0.0f;
    const float* fb = filt + (size_t)n * AANG * NN;
    for (int ch = 0; ch < AANG / ACH; ++ch) {
        __syncthreads();
        // pair staging: idx covers 4 columns; v = f[c..c+3], nx = f[c+4]
        // (nx may read the first element of the NEXT row at c4==63 -- that
        // value is only ever multiplied by frac==0 or guarded off, and is a
        // finite float inside the filt/P workspace).
        for (int idx = tid; idx < ACH * (NN / 4); idx += 1024) {
            int q = idx >> 6;
            int c4 = idx & 63;
            const float* rowp = &fb[(size_t)(ch * ACH + q) * NN + c4 * 4];
            float4 v = *(const float4*)rowp;
            float nx = rowp[4];
            *(float4*)&cols2[q][c4 * 4]     = make_float4(v.x, v.y, v.y, v.z);
            *(float4*)&cols2[q][c4 * 4 + 2] = make_float4(v.z, v.w, v.w, nx);
        }
        __syncthreads();
#pragma unroll 4
        for (int q = 0; q < ACH; ++q) {
            int aa = ch * ACH + q;
            float t = yr * cs[aa] - xr * sn[aa] + 128.0f;
            float i0f = floorf(t);
            int i0 = (int)i0f;
            float frac = t - i0f;
            int c0 = iclamp(i0, 0, NN - 1);
            float2 pr = cols2[q][c0];           // one ds_read_b64
            float val = (1.0f - frac) * pr.x + frac * pr.y;
            if (t >= 0.0f && t <= 255.0f) acc += val;
        }
    }
    bool inside = (xr * xr + yr * yr) <= 16384.0f;
    out[((size_t)(n * NN + r)) * NN + col] = inside ? acc * (float)(M_PI / 360.0) : 0.0f;
}

extern "C" void kernel_launch(void* const* d_in, const int* in_sizes, int n_in,
                              void* d_out, int out_size, void* d_ws, size_t ws_size,
                              hipStream_t stream) {
    const float* x  = (const float*)d_in[0];
    const float* Wq = (const float*)d_in[1];
    const float* bq = (const float*)d_in[2];
    const float* Wk = (const float*)d_in[3];
    const float* bk = (const float*)d_in[4];
    const float* Wv = (const float*)d_in[5];
    const float* bv = (const float*)d_in[6];
    float* out = (float*)d_out;
    float* ws = (float*)d_ws;

    const size_t SZ = (size_t)BCH * NN * AANG;
    float* P     = ws;           // partial[2][n][a][x]
    float* Q     = P + 2 * SZ;
    float* Kt    = Q + SZ;       // transposed: Kt[n][j][i] (attn reads coalesced)
    float* V     = Kt + SZ;      // row-major (attn PV reads coalesced)
    float* att_t = V + SZ;
    float* WqT   = att_t;        // alias: W-transposes dead before attn writes att_t
    float* WkT   = WqT + AANG * AANG;
    float* WvT   = WkT + AANG * AANG;
    float* filt  = P;            // alias: partials dead after qkv

    radon_kernel<<<BCH * 2 * 30, 1024, 0, stream>>>(x, P, Wq, Wk, Wv, WqT, WkT, WvT);
    qkv_kernel<<<BCH * (NN / 8), 256, 0, stream>>>(P, WqT, bq, WkT, bk, WvT, bv, Q, Kt, V);
    attn_kernel<<<BCH * (NN / 8), 256, 0, stream>>>(Q, Kt, V, att_t);
    filter_kernel<<<BCH * AANG, NN, 0, stream>>>(att_t, filt);
    backproj_kernel<<<BCH * (NN / 4), 1024, 0, stream>>>(filt, out);
}

// Round 10
// 359.051 us; speedup vs baseline: 1.0147x; 1.0147x over previous
//
#include <hip/hip_runtime.h>

#define AANG 180
#define NN 256
#define BCH 12

#ifndef M_PI
#define M_PI 3.14159265358979323846
#endif

__device__ __forceinline__ int iclamp(int v, int lo, int hi) {
    return v < lo ? lo : (v > hi ? hi : v);
}

// DPP row_ror add: v += rotate-within-16-lane-row(v, N). VALU only, no LDS pipe.
template <int CTRL>
__device__ __forceinline__ float dpp_add(float v) {
    int r = __builtin_amdgcn_update_dpp(0, __float_as_int(v), CTRL, 0xF, 0xF, true);
    return v + __int_as_float(r);
}

// ---------------- Radon v19 (R21 verbatim, measured 163us): 90-deg pairing +
// MLP-phased trip body. P1: 12 ds_read_b64 back-to-back; P2: 6 lerps; P3: 6
// interleaved DPP chains + batched atomics.
#define LSTR2 259
#define NPAIRS 65

__global__ __launch_bounds__(1024, 4)
void radon_kernel(const float* __restrict__ x, float* __restrict__ partial,
                  const float* __restrict__ Wq, const float* __restrict__ Wk,
                  const float* __restrict__ Wv, float* __restrict__ WqT,
                  float* __restrict__ WkT, float* __restrict__ WvT) {
    __shared__ float2 ptile[NPAIRS * LSTR2];  // 134,680 B
    __shared__ float rowsum[3][257];          // 3,084 B
    int blk = blockIdx.x;        // ((n*2)+h)*30 + g
    int tid = threadIdx.x;

    // --- wtrans prologue: 720 blocks x 45 elements = 32400 (exact) ---
    if (tid < 45) {
        int idx = blk * 45 + tid;
        int p = idx / AANG;
        int j = idx - p * AANG;
        int src = j * AANG + p;
        WqT[idx] = Wq[src];
        WkT[idx] = Wk[src];
        WvT[idx] = Wv[src];
    }

    int g = blk % 30;            // angle group: theta = 3g + k, k=0..2
    int t = blk / 30;
    int h = t & 1;
    int n = t >> 1;
    const float* img = x + (size_t)n * NN * NN;

    int l = tid & 63;            // lane in wave
    int wv = tid >> 6;           // wave 0..15
    int fxl = l & 15;            // fx within wave
    int sub = l >> 4;            // i-phase 0..3 (= DPP row id)
    int fx_i = wv * 16 + fxl;    // detector column 0..255
    float fx = (float)fx_i;

    if (tid < 3 * 257) ((float*)rowsum)[tid] = 0.0f;  // zeroed before 1st sync

    // per-angle constants (theta in [0,89] -> c >= cos(89deg) > 0.017)
    float c[3], s[3], xcon[3], dcon[3], acc[3];
#pragma unroll
    for (int k = 0; k < 3; ++k) {
        int a = 3 * g + k;
        float th = (float)((double)a * (M_PI / 180.0));
        c[k] = cosf(th);
        s[k] = sinf(th);
        float kx = -128.0f * (c[k] + s[k] - 1.0f);
        float ky = -128.0f * (c[k] - s[k] - 1.0f);
        xcon[k] = c[k] * fx + kx;    // sx = fma(s, fy, xcon)
        dcon[k] = -s[k] * fx + ky;   // sy = fma(c, fy, dcon)
        acc[k] = 0.0f;
    }

    for (int b = 0; b < 2; ++b) {
        int bb = h * 2 + b;                 // global band 0..3 (64 rows each)
        int R0 = bb * 64 - 1;               // valid floor(sy) in [R0, R0+lrmax]
        unsigned lrmax = (bb == 3) ? 64u : 63u;
        int npr = (int)lrmax + 1;           // pairs staged: lr = 0..lrmax
        float R0f = (float)R0;              // row guard passes <=> sy in [R0f, R1f)
        float R1f = (float)(R0 + (int)lrmax + 1);

        if (b) __syncthreads();             // band0 compute done before restage
        // stage pairs: ptile[r*LSTR2+cc] = {img[R0+r][cc-1], img[R0+r+1][cc-1]}
        for (int idx = tid; idx < npr * LSTR2; idx += 1024) {
            int r = idx / LSTR2;
            int cc = idx - r * LSTR2;
            int gc = cc - 1;
            int gr0 = R0 + r;
            int gr1 = gr0 + 1;
            bool cok = (gc >= 0) && (gc < NN);
            float v0 = (cok && gr0 >= 0 && gr0 < NN) ? img[gr0 * NN + gc] : 0.0f;
            float v1 = (cok && gr1 < NN) ? img[gr1 * NN + gc] : 0.0f;
            ptile[idx] = make_float2(v0, v1);
        }
        __syncthreads();

        // per-lane 3-angle union of valid-i intervals (conservative slack;
        // in-loop guard enforces exactness); i ranges over [0, 257)
        int ilo = 257, ihi = 0;
#pragma unroll
        for (int k = 0; k < 3; ++k) {
            float t0 = (R0f - dcon[k]) / c[k];   // c > 0 -> t0 < t1
            float t1 = (R1f - dcon[k]) / c[k];
            int lo_k = max(0, (int)floorf(t0));
            int hi_k = min(257, (int)ceilf(t1) + 1);
            if (hi_k > lo_k) {
                ilo = min(ilo, lo_k);
                ihi = max(ihi, hi_k);
            }
        }
        // wave-uniform interval -> lockstep loop
        for (int off = 1; off < 64; off <<= 1) {
            ilo = min(ilo, __shfl_xor(ilo, off));
            ihi = max(ihi, __shfl_xor(ihi, off));
        }

        for (int i = ilo + sub; i < ihi; i += 8) {
            int iB = i + 4;
            float fyA = (float)i;
            float fyB = (float)iB;
            bool inbB = (iB < ihi);

            // ---- P1: addresses + ALL 12 ds_read_b64 issued together ----
            float2 lo2v[6], hi2v[6];
            float wxv[6], wyv[6];
            bool okv[6];
#pragma unroll
            for (int k = 0; k < 3; ++k) {
                {   // sample A
                    float sy = __builtin_fmaf(c[k], fyA, dcon[k]);
                    float sx = __builtin_fmaf(s[k], fyA, xcon[k]);
                    float iyf = floorf(sy), ixf = floorf(sx);
                    int lr = (int)iyf - R0, lc = (int)ixf + 1;
                    bool ok = ((unsigned)lr <= lrmax) & ((unsigned)lc <= 256u);
                    int ad = ok ? (lr * LSTR2 + lc) : 0;
                    lo2v[k] = ptile[ad];
                    hi2v[k] = ptile[ad + 1];
                    wxv[k] = sx - ixf;
                    wyv[k] = sy - iyf;
                    okv[k] = ok;
                }
                {   // sample B
                    float sy = __builtin_fmaf(c[k], fyB, dcon[k]);
                    float sx = __builtin_fmaf(s[k], fyB, xcon[k]);
                    float iyf = floorf(sy), ixf = floorf(sx);
                    int lr = (int)iyf - R0, lc = (int)ixf + 1;
                    bool ok = inbB & ((unsigned)lr <= lrmax) & ((unsigned)lc <= 256u);
                    int ad = ok ? (lr * LSTR2 + lc) : 0;
                    lo2v[3 + k] = ptile[ad];
                    hi2v[3 + k] = ptile[ad + 1];
                    wxv[3 + k] = sx - ixf;
                    wyv[3 + k] = sy - iyf;
                    okv[3 + k] = ok;
                }
            }

            // ---- P2: all 6 lerps + column accumulates ----
            bool coliA = (i < 256), rowiA = (i >= 1);
            bool coliB = (iB < 256);
            float vA[3], vB[3];
#pragma unroll
            for (int k = 0; k < 3; ++k) {
                float wy = wyv[k], wx = wxv[k];
                float wx1 = 1.0f - wx, wy1 = 1.0f - wy;
                float v = wy1 * (wx1 * lo2v[k].x + wx * hi2v[k].x) +
                          wy  * (wx1 * lo2v[k].y + wx * hi2v[k].y);
                acc[k] += (okv[k] && coliA) ? v : 0.0f;
                vA[k] = (okv[k] && rowiA) ? v : 0.0f;
            }
#pragma unroll
            for (int k = 0; k < 3; ++k) {
                float wy = wyv[3 + k], wx = wxv[3 + k];
                float wx1 = 1.0f - wx, wy1 = 1.0f - wy;
                float v = wy1 * (wx1 * lo2v[3 + k].x + wx * hi2v[3 + k].x) +
                          wy  * (wx1 * lo2v[3 + k].y + wx * hi2v[3 + k].y);
                acc[k] += (okv[3 + k] && coliB) ? v : 0.0f;
                vB[k] = okv[3 + k] ? v : 0.0f;   // iB >= 4 so rowi always true
            }

            // ---- P3: 6 independent DPP chains, interleaved ----
            float rA0 = vA[0], rA1 = vA[1], rA2 = vA[2];
            float rB0 = vB[0], rB1 = vB[1], rB2 = vB[2];
            rA0 = dpp_add<0x121>(rA0); rA1 = dpp_add<0x121>(rA1);
            rA2 = dpp_add<0x121>(rA2); rB0 = dpp_add<0x121>(rB0);
            rB1 = dpp_add<0x121>(rB1); rB2 = dpp_add<0x121>(rB2);
            rA0 = dpp_add<0x122>(rA0); rA1 = dpp_add<0x122>(rA1);
            rA2 = dpp_add<0x122>(rA2); rB0 = dpp_add<0x122>(rB0);
            rB1 = dpp_add<0x122>(rB1); rB2 = dpp_add<0x122>(rB2);
            rA0 = dpp_add<0x124>(rA0); rA1 = dpp_add<0x124>(rA1);
            rA2 = dpp_add<0x124>(rA2); rB0 = dpp_add<0x124>(rB0);
            rB1 = dpp_add<0x124>(rB1); rB2 = dpp_add<0x124>(rB2);
            rA0 = dpp_add<0x128>(rA0); rA1 = dpp_add<0x128>(rA1);
            rA2 = dpp_add<0x128>(rA2); rB0 = dpp_add<0x128>(rB0);
            rB1 = dpp_add<0x128>(rB1); rB2 = dpp_add<0x128>(rB2);
            if (fxl == 0) {
                atomicAdd(&rowsum[0][i], rA0);
                atomicAdd(&rowsum[1][i], rA1);
                atomicAdd(&rowsum[2][i], rA2);
                if (inbB) {
                    atomicAdd(&rowsum[0][iB], rB0);
                    atomicAdd(&rowsum[1][iB], rB1);
                    atomicAdd(&rowsum[2][iB], rB2);
                }
            }
        }
    }

    __syncthreads();
    size_t base = (((size_t)h * BCH + n) * AANG);
    // column part: sum the 4 sub-phases (lanes l, l^16, l^32, l^48 share fx)
#pragma unroll
    for (int k = 0; k < 3; ++k) {
        acc[k] += __shfl_xor(acc[k], 16);
        acc[k] += __shfl_xor(acc[k], 32);
    }
    if (sub == 0) {
#pragma unroll
        for (int k = 0; k < 3; ++k)
            partial[(base + (3 * g + k)) * NN + fx_i] = acc[k];
    }
    // row part: sino(theta+90)[256-i] = rowsum[k][i], i = 1..256
    if (tid < 3 * 257) {
        int k = tid / 257;
        int i = tid - k * 257;
        if (i >= 1)
            partial[(base + (3 * g + k + 90)) * NN + (256 - i)] = rowsum[k][i];
    }
}

// ---------------- QKV v8 (R25): 4 rows/block, 192 threads, 768 blocks.
// R23 post-mortem: tail is grid-starved (384 blocks = 1.5/CU). Halving rows
// per block doubles the grid (3 blocks/CU, 9 waves/CU) and 192 threads lifts
// lane efficiency 70%->94%. Per-output fp math identical (same dot order).
__global__ void qkv_kernel(const float* __restrict__ partial,
                           const float* __restrict__ WqT, const float* __restrict__ bq,
                           const float* __restrict__ WkT, const float* __restrict__ bk,
                           const float* __restrict__ WvT, const float* __restrict__ bv,
                           float* __restrict__ Q, float* __restrict__ Kt,
                           float* __restrict__ V) {
    __shared__ float srow_t[AANG][4];
    int blk = blockIdx.x;  // n*64 + i4
    int n = blk >> 6;
    int i0 = (blk & 63) * 4;
    int tid = threadIdx.x;  // 192
    const size_t HOFF = (size_t)BCH * AANG * NN;
    if (tid < AANG) {
        size_t idx = (((size_t)n) * AANG + tid) * NN + i0;
        float4 p0 = *(const float4*)&partial[idx];
        float4 q0 = *(const float4*)&partial[idx + HOFF];
        srow_t[tid][0] = p0.x + q0.x;
        srow_t[tid][1] = p0.y + q0.y;
        srow_t[tid][2] = p0.z + q0.z;
        srow_t[tid][3] = p0.w + q0.w;
    }
    __syncthreads();
    if (tid < AANG) {
        int j = tid;
        float aq[4], ak[4], av[4];
        float bqv = bq[j], bkv = bk[j], bvv = bv[j];
        for (int r = 0; r < 4; ++r) { aq[r] = bqv; ak[r] = bkv; av[r] = bvv; }
#pragma unroll 4
        for (int p = 0; p < AANG; ++p) {
            float wq = WqT[p * AANG + j];
            float wk = WkT[p * AANG + j];
            float wv = WvT[p * AANG + j];
            float4 sv0 = *(const float4*)&srow_t[p][0];
            aq[0] += sv0.x * wq; ak[0] += sv0.x * wk; av[0] += sv0.x * wv;
            aq[1] += sv0.y * wq; ak[1] += sv0.y * wk; av[1] += sv0.y * wv;
            aq[2] += sv0.z * wq; ak[2] += sv0.z * wk; av[2] += sv0.z * wv;
            aq[3] += sv0.w * wq; ak[3] += sv0.w * wk; av[3] += sv0.w * wv;
        }
        for (int r = 0; r < 4; ++r) {
            size_t qb = ((size_t)(n * NN + i0 + r)) * AANG + j;
            Q[qb] = aq[r];  // coalesced over j
            V[qb] = av[r];  // row-major, coalesced over j
        }
        size_t kb = ((size_t)(n * AANG + j)) * NN + i0;
        *(float4*)&Kt[kb] = make_float4(ak[0], ak[1], ak[2], ak[3]);
    }
}

// ---------------- Attention v8 (R25): 4 rows/block, 768 blocks (12 waves/CU,
// was 6). Same per-row math and reduction sequence as v7.
__global__ void attn_kernel(const float* __restrict__ Q, const float* __restrict__ Kt,
                            const float* __restrict__ V, float* __restrict__ att_t) {
    __shared__ float qrow[4][AANG];
    __shared__ float prob[4][NN];
    __shared__ float wm[4][4], wsm[4][4];
    int blk = blockIdx.x;  // n*64 + i4
    int n = blk >> 6;
    int i0 = (blk & 63) * 4;
    int tid = threadIdx.x;  // 256: key index k
    int wid = tid >> 6;
    if (tid < AANG) {
#pragma unroll
        for (int r = 0; r < 4; ++r)
            qrow[r][tid] = Q[((size_t)(n * NN + i0 + r)) * AANG + tid];
    }
    __syncthreads();
    float d[4];
#pragma unroll
    for (int r = 0; r < 4; ++r) d[r] = 0.0f;
    const float* kcol = Kt + (size_t)n * AANG * NN + tid;  // lane k: coalesced
#pragma unroll 3
    for (int jj = 0; jj < AANG / 4; ++jj) {
        float kv0 = kcol[(size_t)(jj * 4 + 0) * NN];
        float kv1 = kcol[(size_t)(jj * 4 + 1) * NN];
        float kv2 = kcol[(size_t)(jj * 4 + 2) * NN];
        float kv3 = kcol[(size_t)(jj * 4 + 3) * NN];
#pragma unroll
        for (int r = 0; r < 4; ++r) {
            float4 qv = *(const float4*)&qrow[r][jj * 4];
            d[r] += qv.x * kv0;
            d[r] += qv.y * kv1;
            d[r] += qv.z * kv2;
            d[r] += qv.w * kv3;
        }
    }
    const float rs = 0.0745355992f;  // 1/sqrt(180)
    float l[4], m[4], e[4], s[4];
#pragma unroll
    for (int r = 0; r < 4; ++r) { l[r] = d[r] * rs; m[r] = l[r]; }
    for (int off = 32; off > 0; off >>= 1) {
#pragma unroll
        for (int r = 0; r < 4; ++r) m[r] = fmaxf(m[r], __shfl_xor(m[r], off));
    }
    if ((tid & 63) == 0) {
#pragma unroll
        for (int r = 0; r < 4; ++r) wm[r][wid] = m[r];
    }
    __syncthreads();
#pragma unroll
    for (int r = 0; r < 4; ++r) {
        float mx = fmaxf(fmaxf(wm[r][0], wm[r][1]), fmaxf(wm[r][2], wm[r][3]));
        e[r] = expf(l[r] - mx);
        s[r] = e[r];
    }
    for (int off = 32; off > 0; off >>= 1) {
#pragma unroll
        for (int r = 0; r < 4; ++r) s[r] += __shfl_xor(s[r], off);
    }
    if ((tid & 63) == 0) {
#pragma unroll
        for (int r = 0; r < 4; ++r) wsm[r][wid] = s[r];
    }
    __syncthreads();
#pragma unroll
    for (int r = 0; r < 4; ++r) {
        float dn = wsm[r][0] + wsm[r][1] + wsm[r][2] + wsm[r][3];
        prob[r][tid] = e[r] / dn;
    }
    __syncthreads();
    if (tid < AANG) {
        float a[4];
#pragma unroll
        for (int r = 0; r < 4; ++r) a[r] = 0.0f;
        const float* vcol = V + (size_t)n * NN * AANG + tid;  // lane j: coalesced
#pragma unroll 4
        for (int kk = 0; kk < NN / 4; ++kk) {
            float v0 = vcol[(size_t)(kk * 4 + 0) * AANG];
            float v1 = vcol[(size_t)(kk * 4 + 1) * AANG];
            float v2 = vcol[(size_t)(kk * 4 + 2) * AANG];
            float v3 = vcol[(size_t)(kk * 4 + 3) * AANG];
#pragma unroll
            for (int r = 0; r < 4; ++r) {
                float4 p4 = *(const float4*)&prob[r][kk * 4];
                a[r] += p4.x * v0;
                a[r] += p4.y * v1;
                a[r] += p4.z * v2;
                a[r] += p4.w * v3;
            }
        }
        size_t ob = ((size_t)(n * AANG + tid)) * NN + i0;
        *(float4*)&att_t[ob] = make_float4(a[0], a[1], a[2], a[3]);
    }
}

// ---------------- Ramp filter v3 (R23): fully-unrolled LITERAL coefficients.
__global__ void filter_kernel(const float* __restrict__ att_t, float* __restrict__ filt) {
    __shared__ float scol[512];  // [128..383] = data, rest 0
    int blk = blockIdx.x;  // n*AANG + a
    int tid = threadIdx.x;
    const float* src = &att_t[(size_t)blk * NN];
    scol[tid] = (tid >= 128) ? src[tid - 128] : 0.0f;
    scol[tid + 256] = (tid < 128) ? src[tid + 128] : 0.0f;
    __syncthreads();
    const float* c = &scol[tid + 128];
    float acc = 0.5f * c[0];
#pragma unroll
    for (int m = 0; m < 128; ++m) {
        int d = 2 * m + 1;
        float df = (float)d;
        float cf = -2.0f / (((float)(M_PI * M_PI) * df) * df);  // folded to literal
        acc += cf * (c[-d] + c[d]);
    }
    filt[(size_t)blk * NN + tid] = acc;
}

// ---------------- Backprojection v6 (R23): pair-interleaved float2 tile.
#define ACH 36
__global__ __launch_bounds__(1024)
void backproj_kernel(const float* __restrict__ filt, float* __restrict__ out) {
    __shared__ float2 cols2[ACH][NN];   // 73,728 B
    __shared__ float cs[AANG], sn[AANG];
    int blk = blockIdx.x;  // n*64 + rg
    int n = blk >> 6;
    int rg = blk & 63;
    int tid = threadIdx.x;
    int col = tid & 255;
    int rslot = tid >> 8;
    int r = rg * 4 + rslot;
    if (tid < AANG) {
        float th = (float)((double)tid * (M_PI / 180.0));
        cs[tid] = cosf(th);
        sn[tid] = sinf(th);
    }
    float xr = (float)(r - 128);
    float yr = (float)(col - 128);
    float acc = 0.0f;
    const float* fb = filt + (size_t)n * AANG * NN;
    for (int ch = 0; ch < AANG / ACH; ++ch) {
        __syncthreads();
        for (int idx = tid; idx < ACH * (NN / 4); idx += 1024) {
            int q = idx >> 6;
            int c4 = idx & 63;
            const float* rowp = &fb[(size_t)(ch * ACH + q) * NN + c4 * 4];
            float4 v = *(const float4*)rowp;
            float nx = rowp[4];
            *(float4*)&cols2[q][c4 * 4]     = make_float4(v.x, v.y, v.y, v.z);
            *(float4*)&cols2[q][c4 * 4 + 2] = make_float4(v.z, v.w, v.w, nx);
        }
        __syncthreads();
#pragma unroll 4
        for (int q = 0; q < ACH; ++q) {
            int aa = ch * ACH + q;
            float t = yr * cs[aa] - xr * sn[aa] + 128.0f;
            float i0f = floorf(t);
            int i0 = (int)i0f;
            float frac = t - i0f;
            int c0 = iclamp(i0, 0, NN - 1);
            float2 pr = cols2[q][c0];           // one ds_read_b64
            float val = (1.0f - frac) * pr.x + frac * pr.y;
            if (t >= 0.0f && t <= 255.0f) acc += val;
        }
    }
    bool inside = (xr * xr + yr * yr) <= 16384.0f;
    out[((size_t)(n * NN + r)) * NN + col] = inside ? acc * (float)(M_PI / 360.0) : 0.0f;
}

extern "C" void kernel_launch(void* const* d_in, const int* in_sizes, int n_in,
                              void* d_out, int out_size, void* d_ws, size_t ws_size,
                              hipStream_t stream) {
    const float* x  = (const float*)d_in[0];
    const float* Wq = (const float*)d_in[1];
    const float* bq = (const float*)d_in[2];
    const float* Wk = (const float*)d_in[3];
    const float* bk = (const float*)d_in[4];
    const float* Wv = (const float*)d_in[5];
    const float* bv = (const float*)d_in[6];
    float* out = (float*)d_out;
    float* ws = (float*)d_ws;

    const size_t SZ = (size_t)BCH * NN * AANG;
    float* P     = ws;           // partial[2][n][a][x]
    float* Q     = P + 2 * SZ;
    float* Kt    = Q + SZ;       // transposed: Kt[n][j][i] (attn reads coalesced)
    float* V     = Kt + SZ;      // row-major (attn PV reads coalesced)
    float* att_t = V + SZ;
    float* WqT   = att_t;        // alias: W-transposes dead before attn writes att_t
    float* WkT   = WqT + AANG * AANG;
    float* WvT   = WkT + AANG * AANG;
    float* filt  = P;            // alias: partials dead after qkv

    radon_kernel<<<BCH * 2 * 30, 1024, 0, stream>>>(x, P, Wq, Wk, Wv, WqT, WkT, WvT);
    qkv_kernel<<<BCH * (NN / 4), 192, 0, stream>>>(P, WqT, bq, WkT, bk, WvT, bv, Q, Kt, V);
    attn_kernel<<<BCH * (NN / 4), 256, 0, stream>>>(Q, Kt, V, att_t);
    filter_kernel<<<BCH * AANG, NN, 0, stream>>>(att_t, filt);
    backproj_kernel<<<BCH * (NN / 4), 1024, 0, stream>>>(filt, out);
}